// Round 5
// baseline (265.167 us; speedup 1.0000x reference)
//
#include <hip/hip_runtime.h>
#include <math.h>

// CRF log-likelihood, B=2048, T=80, L=128 — v5: fwd+bwd meet-in-the-middle,
// both chains interleaved in ONE wave (2x ILP, half the serial chain length).
// fwd: a_t = exp(x_t) o (a_{t-1} · E),  t = 1..39,  a_0 = exp(start + x_0)
// bwd: v_t = exp(x_t) o (E · v_{t+1}),  t = 78..40, v_79 = exp(x_79 + end)
// Z = (a_39 · E) · v_40.  A-operands (permuted E^T and E) live in AGPRs.
// State permutation g makes MFMA C-layout output pack directly into the next
// step's B-fragments (register-only recurrence, no LDS, no barriers).

#define CRF_B 2048
#define CRF_T 80
#define CRF_L 128

typedef __attribute__((ext_vector_type(8))) short bf16x8_t;
typedef __attribute__((ext_vector_type(4))) float f32x4_t;

union bfrag { bf16x8_t v; unsigned u[4]; unsigned short s[8]; };

__device__ __forceinline__ unsigned pack2(float lo, float hi) {
    return (__float_as_uint(lo) >> 16) | (__float_as_uint(hi) & 0xFFFF0000u);
}
__device__ __forceinline__ unsigned short bft(float f) {
    return (unsigned short)(__float_as_uint(f) >> 16);
}

__global__ __launch_bounds__(64, 1) void crf_v5_kernel(
    const float* __restrict__ x,           // [B,T,L]
    const float* __restrict__ trans,       // [L,L]
    const float* __restrict__ start_trans, // [L]
    const float* __restrict__ end_trans,   // [L]
    const int*   __restrict__ y,           // [B,T]
    float* __restrict__ out)               // [B]
{
    const int lane = threadIdx.x;
    const int q    = lane >> 4;
    const int n16  = lane & 15;
    const int row0 = blockIdx.x * 16;
    const int brow = row0 + n16;

    const float* xr = x + (size_t)brow * (CRF_T * CRF_L);
    const int*   yb = y + brow * CRF_T;

    // ---------------- numerator: 4 lanes (quads) per row ----------------
    float nume = 0.f;
    #pragma unroll
    for (int i = 0; i < 20; ++i) {
        const int t  = 4 * i + q;
        const int yt = yb[t];
        nume += xr[t * CRF_L + yt];
        nume += (t < CRF_T - 1) ? trans[yt * CRF_L + yb[t + 1]] : end_trans[yt];
        if (t == 0) nume += start_trans[yt];
    }
    nume += __shfl_xor(nume, 16);
    nume += __shfl_xor(nume, 32);

    // ---------------- A-frags (registers/AGPRs) ----------------
    // slot v = 32kk+8q+j  ->  true state s = g^-1(v) = ((2kk+(j>>2))<<4)|(q<<2)|(j&3)
    // fwd: A'[m][v] = exp(trans[s][m])   (E^T)
    // bwd: A'[m][v] = exp(trans[m][s])   (E)
    bfrag Aff[8][4], Afb[8][4];
    #pragma unroll
    for (int mt = 0; mt < 8; ++mt) {
        const int m = 16 * mt + n16;
        #pragma unroll
        for (int kk = 0; kk < 4; ++kk) {
            #pragma unroll
            for (int j = 0; j < 8; ++j) {
                const int s = ((2 * kk + (j >> 2)) << 4) | (q << 2) | (j & 3);
                Aff[mt][kk].s[j] = bft(__expf(trans[s * CRF_L + m]));
                Afb[mt][kk].s[j] = bft(__expf(trans[m * CRF_L + s]));
            }
        }
    }

    // ---------------- x buffers (distance-2 ping-pong, both directions) ----------------
    f32x4_t xF[2][8], xB[2][8], x0t[8], x9t[8];
    #pragma unroll
    for (int mt = 0; mt < 8; ++mt) {
        const int c = 16 * mt + 4 * q;
        x0t[mt]   = *(const f32x4_t*)&xr[ 0 * CRF_L + c];
        x9t[mt]   = *(const f32x4_t*)&xr[79 * CRF_L + c];
        xF[1][mt] = *(const f32x4_t*)&xr[ 1 * CRF_L + c];
        xF[0][mt] = *(const f32x4_t*)&xr[ 2 * CRF_L + c];
        xB[1][mt] = *(const f32x4_t*)&xr[78 * CRF_L + c];
        xB[0][mt] = *(const f32x4_t*)&xr[77 * CRF_L + c];
    }

    // ---------------- chain init ----------------
    bfrag BfF[4], BfB[4];
    f32x4_t accF[8], accB[8];
    float crunF = 0.f, crunB = 0.f, invF = 1.f, invB = 1.f;

    #pragma unroll
    for (int mt = 0; mt < 8; ++mt) {
        const int c = 16 * mt + 4 * q;
        const f32x4_t st4 = *(const f32x4_t*)&start_trans[c];
        const f32x4_t en4 = *(const f32x4_t*)&end_trans[c];
        #pragma unroll
        for (int r = 0; r < 4; ++r) {
            accF[mt][r] = __expf(st4[r] + x0t[mt][r]);
            accB[mt][r] = __expf(en4[r] + x9t[mt][r]);
        }
    }
    #pragma unroll
    for (int mt = 0; mt < 8; ++mt) {
        BfF[mt >> 1].u[2 * (mt & 1) + 0] = pack2(accF[mt][0], accF[mt][1]);
        BfF[mt >> 1].u[2 * (mt & 1) + 1] = pack2(accF[mt][2], accF[mt][3]);
        BfB[mt >> 1].u[2 * (mt & 1) + 0] = pack2(accB[mt][0], accB[mt][1]);
        BfB[mt >> 1].u[2 * (mt & 1) + 1] = pack2(accB[mt][2], accB[mt][3]);
    }

    // ---------------- interleaved pair-step (fwd t=k, bwd t=79-k) ----------------
    auto pairstep = [&](int k, f32x4_t (&xf)[8], f32x4_t (&xb)[8]) {
        #pragma unroll
        for (int mt = 0; mt < 8; ++mt) {
            f32x4_t aF = {0.f, 0.f, 0.f, 0.f};
            f32x4_t aB = {0.f, 0.f, 0.f, 0.f};
            #pragma unroll
            for (int kk = 0; kk < 4; ++kk) {
                aF = __builtin_amdgcn_mfma_f32_16x16x32_bf16(Aff[mt][kk].v, BfF[kk].v, aF, 0, 0, 0);
                aB = __builtin_amdgcn_mfma_f32_16x16x32_bf16(Afb[mt][kk].v, BfB[kk].v, aB, 0, 0, 0);
            }
            accF[mt] = aF;
            accB[mt] = aB;
        }
        const bool ap = (k & 3) == 0;  // apply invM pending from renorm at k-1
        #pragma unroll
        for (int mt = 0; mt < 8; ++mt) {
            #pragma unroll
            for (int r = 0; r < 4; ++r) {
                float eF = __expf(xf[mt][r]);
                float eB = __expf(xb[mt][r]);
                if (ap) { eF *= invF; eB *= invB; }
                accF[mt][r] *= eF;
                accB[mt][r] *= eB;
            }
        }
        if (((k & 3) == 3) && (k < 39)) {
            float mF = accF[0][0], mB = accB[0][0];
            #pragma unroll
            for (int mt = 0; mt < 8; ++mt)
                #pragma unroll
                for (int r = 0; r < 4; ++r) {
                    mF = fmaxf(mF, accF[mt][r]);
                    mB = fmaxf(mB, accB[mt][r]);
                }
            mF = fmaxf(mF, __shfl_xor(mF, 16)); mF = fmaxf(mF, __shfl_xor(mF, 32));
            mB = fmaxf(mB, __shfl_xor(mB, 16)); mB = fmaxf(mB, __shfl_xor(mB, 32));
            crunF += __logf(mF); invF = 1.0f / mF;
            crunB += __logf(mB); invB = 1.0f / mB;
        }
        #pragma unroll
        for (int mt = 0; mt < 8; ++mt) {
            BfF[mt >> 1].u[2 * (mt & 1) + 0] = pack2(accF[mt][0], accF[mt][1]);
            BfF[mt >> 1].u[2 * (mt & 1) + 1] = pack2(accF[mt][2], accF[mt][3]);
            BfB[mt >> 1].u[2 * (mt & 1) + 0] = pack2(accB[mt][0], accB[mt][1]);
            BfB[mt >> 1].u[2 * (mt & 1) + 1] = pack2(accB[mt][2], accB[mt][3]);
        }
        if (k + 2 <= 39) {
            #pragma unroll
            for (int mt = 0; mt < 8; ++mt)
                xf[mt] = *(const f32x4_t*)&xr[(k + 2) * CRF_L + 16 * mt + 4 * q];
        }
        if (k <= 37) {
            #pragma unroll
            for (int mt = 0; mt < 8; ++mt)
                xb[mt] = *(const f32x4_t*)&xr[(77 - k) * CRF_L + 16 * mt + 4 * q];
        }
    };

    for (int k = 1; k <= 37; k += 2) {       // pairs (1,2)..(37,38)
        pairstep(k,     xF[1], xB[1]);
        pairstep(k + 1, xF[0], xB[0]);
    }

    // ---------------- k = 39: final matvec step, immediate renorm ----------------
    {
        #pragma unroll
        for (int mt = 0; mt < 8; ++mt) {
            f32x4_t aF = {0.f, 0.f, 0.f, 0.f};
            f32x4_t aB = {0.f, 0.f, 0.f, 0.f};
            #pragma unroll
            for (int kk = 0; kk < 4; ++kk) {
                aF = __builtin_amdgcn_mfma_f32_16x16x32_bf16(Aff[mt][kk].v, BfF[kk].v, aF, 0, 0, 0);
                aB = __builtin_amdgcn_mfma_f32_16x16x32_bf16(Afb[mt][kk].v, BfB[kk].v, aB, 0, 0, 0);
            }
            #pragma unroll
            for (int r = 0; r < 4; ++r) {
                accF[mt][r] = aF[r] * __expf(xF[1][mt][r]);   // a_39
                accB[mt][r] = aB[r] * __expf(xB[1][mt][r]);   // v_40
            }
        }
        float mF = accF[0][0], mB = accB[0][0];
        #pragma unroll
        for (int mt = 0; mt < 8; ++mt)
            #pragma unroll
            for (int r = 0; r < 4; ++r) {
                mF = fmaxf(mF, accF[mt][r]);
                mB = fmaxf(mB, accB[mt][r]);
            }
        mF = fmaxf(mF, __shfl_xor(mF, 16)); mF = fmaxf(mF, __shfl_xor(mF, 32));
        mB = fmaxf(mB, __shfl_xor(mB, 16)); mB = fmaxf(mB, __shfl_xor(mB, 32));
        crunF += __logf(mF); const float iF = 1.0f / mF;
        crunB += __logf(mB); const float iB = 1.0f / mB;
        #pragma unroll
        for (int mt = 0; mt < 8; ++mt) {
            #pragma unroll
            for (int r = 0; r < 4; ++r) {
                accF[mt][r] *= iF;
                accB[mt][r] *= iB;
            }
            BfF[mt >> 1].u[2 * (mt & 1) + 0] = pack2(accF[mt][0], accF[mt][1]);
            BfF[mt >> 1].u[2 * (mt & 1) + 1] = pack2(accF[mt][2], accF[mt][3]);
        }
    }

    // ---------------- a'_40 = a_39 · E  (no emission), then dot with v_40 ----------------
    float sv = 0.f;
    #pragma unroll
    for (int mt = 0; mt < 8; ++mt) {
        f32x4_t aF = {0.f, 0.f, 0.f, 0.f};
        #pragma unroll
        for (int kk = 0; kk < 4; ++kk)
            aF = __builtin_amdgcn_mfma_f32_16x16x32_bf16(Aff[mt][kk].v, BfF[kk].v, aF, 0, 0, 0);
        #pragma unroll
        for (int r = 0; r < 4; ++r)
            sv += aF[r] * accB[mt][r];
    }
    sv += __shfl_xor(sv, 16);
    sv += __shfl_xor(sv, 32);
    if (lane < 16) out[row0 + n16] = nume - (crunF + crunB + __logf(sv));
}

extern "C" void kernel_launch(void* const* d_in, const int* in_sizes, int n_in,
                              void* d_out, int out_size, void* d_ws, size_t ws_size,
                              hipStream_t stream) {
    const float* x     = (const float*)d_in[0];
    const float* trans = (const float*)d_in[1];
    const float* st    = (const float*)d_in[2];
    const float* et    = (const float*)d_in[3];
    const int*   y     = (const int*)d_in[4];
    float* out = (float*)d_out;

    crf_v5_kernel<<<CRF_B / 16, 64, 0, stream>>>(x, trans, st, et, y, out);
}

// Round 6
// 164.339 us; speedup vs baseline: 1.6135x; 1.6135x over previous
//
#include <hip/hip_runtime.h>
#include <math.h>

// CRF log-likelihood, B=2048, T=80, L=128 — v6: v3's LDS-exchange MFMA
// structure + occupancy via duplication. 4 REAL batch rows per block
// (n16 -> row0 + (n16&3), 4x duplicated into the 16-row MFMA tile) ->
// grid 512 = 2 blocks/CU on all 256 CUs = 2 independent chains/SIMD.
// Renorm every 4 steps, one-step-delayed apply (v4-verified numerics).
// VGPR stays ~80 (A-frags only 32 regs/wave) — no spill.

#define CRF_B 2048
#define CRF_T 80
#define CRF_L 128
#define R_REAL 4

typedef __attribute__((ext_vector_type(8))) short bf16x8_t;
typedef __attribute__((ext_vector_type(4))) float f32x4_t;

__device__ __forceinline__ int pack_bf16_trunc(float lo, float hi) {
    return (int)((__float_as_uint(lo) >> 16) | (__float_as_uint(hi) & 0xFFFF0000u));
}
__device__ __forceinline__ unsigned short bft(float f) {
    return (unsigned short)(__float_as_uint(f) >> 16);
}

__global__ __launch_bounds__(256) void crf_v6_kernel(
    const float* __restrict__ x,           // [B,T,L]
    const float* __restrict__ trans,       // [L,L]
    const float* __restrict__ start_trans, // [L]
    const float* __restrict__ end_trans,   // [L]
    const int*   __restrict__ y,           // [B,T]
    float* __restrict__ out)               // [B]
{
    const int tid  = threadIdx.x;
    const int w    = tid >> 6;     // wave 0..3: owns states [32w, 32w+32)
    const int lane = tid & 63;
    const int quad = lane >> 4;
    const int n16  = lane & 15;    // tile row; real batch row = row0 + (n16&3)
    const int row0 = blockIdx.x * R_REAL;
    const int brow = row0 + (n16 & (R_REAL - 1));

    __shared__ __attribute__((aligned(16))) short Vb[2][16][136]; // bf16 V, dbuf
    __shared__ __attribute__((aligned(16))) float maxb[16][4];    // [row][wave]
    __shared__ __attribute__((aligned(16))) float sumb[16][4];
    __shared__ float numb[R_REAL];

    // ---------------- numerator: wave w -> real row row0+w ----------------
    {
        const int bb = row0 + w;
        const int* yb = y + bb * CRF_T;
        const float* xbn = x + (size_t)bb * CRF_T * CRF_L;
        float p = 0.f;
        for (int t = lane; t < CRF_T; t += 64) {
            const int yt = yb[t];
            p += xbn[t * CRF_L + yt];
            p += (t + 1 < CRF_T) ? trans[yt * CRF_L + yb[t + 1]] : end_trans[yt];
            if (t == 0) p += start_trans[yt];
        }
        #pragma unroll
        for (int off = 1; off <= 32; off <<= 1) p += __shfl_xor(p, off);
        if (lane == 0) numb[w] = p;
    }

    // ---------- A-frags: E^T in registers. A[m][k] = exp(trans[k][m]) ----------
    // 16x16x32 A layout: lane holds A[m = n16][k = 32kk + 8quad + j]
    bf16x8_t Af[2][4];
    #pragma unroll
    for (int mt = 0; mt < 2; ++mt) {
        const int m = 32 * w + 16 * mt + n16;  // global output state
        #pragma unroll
        for (int kk = 0; kk < 4; ++kk) {
            union { bf16x8_t v; unsigned short s[8]; } u;
            #pragma unroll
            for (int j = 0; j < 8; ++j) {
                const int k = 32 * kk + 8 * quad + j;  // input state
                u.s[j] = bft(__expf(trans[k * CRF_L + m]));
            }
            Af[mt][kk] = u.v;
        }
    }

    // per-lane x columns: 4 consecutive states per m-tile -> float4 loads
    const int sc0 = 32 * w + 4 * quad;
    const int sc1 = sc0 + 16;
    const float* xr = x + (size_t)brow * CRF_T * CRF_L;

    f32x4_t ex_end[2], st4[2];
    {
        const f32x4_t e0 = *(const f32x4_t*)&end_trans[sc0];
        const f32x4_t e1 = *(const f32x4_t*)&end_trans[sc1];
        #pragma unroll
        for (int r = 0; r < 4; ++r) {
            ex_end[0][r] = __expf(e0[r]);
            ex_end[1][r] = __expf(e1[r]);
        }
        st4[0] = *(const f32x4_t*)&start_trans[sc0];
        st4[1] = *(const f32x4_t*)&start_trans[sc1];
    }

    f32x4_t P[2];
    float invM = 1.f, crun = 0.f;
    f32x4_t xc[2], xn[2];
    xc[0] = *(const f32x4_t*)&xr[sc0];
    xc[1] = *(const f32x4_t*)&xr[sc1];

    for (int t = 0; t < CRF_T; ++t) {
        // prefetch next step's emissions
        if (t + 1 < CRF_T) {
            xn[0] = *(const f32x4_t*)&xr[(t + 1) * CRF_L + sc0];
            xn[1] = *(const f32x4_t*)&xr[(t + 1) * CRF_L + sc1];
        }

        // delayed renorm: consume maxb written at step t-1 (t = 4,8,...,76)
        const bool ap = (t > 0) && ((t & 3) == 0);
        if (ap) {
            const f32x4_t mb = *(const f32x4_t*)&maxb[n16][0];
            const float M = fmaxf(fmaxf(mb[0], mb[1]), fmaxf(mb[2], mb[3]));
            crun += __logf(M);
            invM  = __builtin_amdgcn_rcpf(M);
        }

        if (t == 0) {
            #pragma unroll
            for (int r = 0; r < 4; ++r) {
                P[0][r] = __expf(st4[0][r] + xc[0][r]);
                P[1][r] = __expf(st4[1][r] + xc[1][r]);
            }
        } else {
            // B-frags: V^T from LDS. B[k][n]: n = n16, k = 32kk+8quad+j
            const short* vrow = &Vb[(t - 1) & 1][n16][0];
            bf16x8_t Bf[4];
            #pragma unroll
            for (int kk = 0; kk < 4; ++kk)
                Bf[kk] = *(const bf16x8_t*)&vrow[32 * kk + 8 * quad];
            #pragma unroll
            for (int mt = 0; mt < 2; ++mt) {
                f32x4_t acc = {0.f, 0.f, 0.f, 0.f};
                #pragma unroll
                for (int kk = 0; kk < 4; ++kk)
                    acc = __builtin_amdgcn_mfma_f32_16x16x32_bf16(Af[mt][kk], Bf[kk], acc, 0, 0, 0);
                #pragma unroll
                for (int r = 0; r < 4; ++r) {
                    float e = __expf(xc[mt][r]);
                    if (ap) e *= invM;
                    P[mt][r] = acc[r] * e;
                }
            }
        }

        // every 4th step: per-row max across this wave's 32 states -> maxb
        if (((t & 3) == 3) && (t < CRF_T - 1)) {
            float g = fmaxf(fmaxf(fmaxf(P[0][0], P[0][1]), fmaxf(P[0][2], P[0][3])),
                            fmaxf(fmaxf(P[1][0], P[1][1]), fmaxf(P[1][2], P[1][3])));
            g = fmaxf(g, __shfl_xor(g, 16));
            g = fmaxf(g, __shfl_xor(g, 32));
            if (lane < 16) maxb[n16][w] = g;
        }

        if (t < CRF_T - 1) {
            // write V_t (bf16 trunc) to the other buffer
            short* dst = &Vb[t & 1][n16][0];
            const int d00 = pack_bf16_trunc(P[0][0], P[0][1]);
            const int d01 = pack_bf16_trunc(P[0][2], P[0][3]);
            const int d10 = pack_bf16_trunc(P[1][0], P[1][1]);
            const int d11 = pack_bf16_trunc(P[1][2], P[1][3]);
            *(int2*)&dst[sc0] = make_int2(d00, d01);
            *(int2*)&dst[sc1] = make_int2(d10, d11);
            __syncthreads();
        }

        xc[0] = xn[0];
        xc[1] = xn[1];
    }

    // ------------- epilogue: log_z = crun + log(sum_s P[s]*exp(end[s])) -------------
    float sv = 0.f;
    #pragma unroll
    for (int mt = 0; mt < 2; ++mt)
    #pragma unroll
    for (int r = 0; r < 4; ++r)
        sv += P[mt][r] * ex_end[mt][r];
    sv += __shfl_xor(sv, 16);
    sv += __shfl_xor(sv, 32);
    if (lane < 16) sumb[n16][w] = sv;
    __syncthreads();
    if (tid < R_REAL) {
        const f32x4_t sb = *(const f32x4_t*)&sumb[tid][0];
        const float S = sb[0] + sb[1] + sb[2] + sb[3];
        // crun of this thread: lane==tid -> n16==tid -> real row row0+tid. OK.
        out[row0 + tid] = numb[tid] - (crun + __logf(S));
    }
}

extern "C" void kernel_launch(void* const* d_in, const int* in_sizes, int n_in,
                              void* d_out, int out_size, void* d_ws, size_t ws_size,
                              hipStream_t stream) {
    const float* x     = (const float*)d_in[0];
    const float* trans = (const float*)d_in[1];
    const float* st    = (const float*)d_in[2];
    const float* et    = (const float*)d_in[3];
    const int*   y     = (const int*)d_in[4];
    float* out = (float*)d_out;

    crf_v6_kernel<<<CRF_B / R_REAL, 256, 0, stream>>>(x, trans, st, et, y, out);
}